// Round 10
// baseline (133.591 us; speedup 1.0000x reference)
//
#include <hip/hip_runtime.h>
#include <hip/hip_bf16.h>

// Grouped GEMM: out[e,s,o] = sum_i x[e,s,i] * w[e,o,i]
// E=8, S=8192 tok/expert, O=512, I=1024, fp32 in/out, bf16 MFMA compute.
// R10: single-barrier phases (4 bars/tile, was 8). LDS writes confined to
//      P2 (A-h0 rows 0-127 + B-DMA) and P3 (A-h1 rows 128-255); P1/P4 are
//      read+MFMA only -> with one bar per phase, concurrent bodies are the
//      same phase and all write/read pairs are buffer- or row-disjoint.
//      Counted vmcnt chain: P2 vm(4), P3 vm(8), P4 vm(8); tail peels to
//      vm(4)/vm(0). A-prefetch lead now 4 phases. Frame else == R9.

#define NE 8
#define NO 512
#define NI 1024
#define NS 8192

#define BM 256
#define BN 256
#define BK 64
#define NT (NI / BK)  // 16 K-tiles

typedef __attribute__((ext_vector_type(4))) float f32x4;
typedef __attribute__((ext_vector_type(4))) short s16x4;
typedef __attribute__((ext_vector_type(8))) short s16x8;

__device__ __forceinline__ s16x4 cvt4(f32x4 a) {
    s16x4 r;
    r[0] = (short)__builtin_bit_cast(unsigned short, __float2bfloat16(a[0]));
    r[1] = (short)__builtin_bit_cast(unsigned short, __float2bfloat16(a[1]));
    r[2] = (short)__builtin_bit_cast(unsigned short, __float2bfloat16(a[2]));
    r[3] = (short)__builtin_bit_cast(unsigned short, __float2bfloat16(a[3]));
    return r;
}

// ---- pass 0: W fp32 -> bf16 row-major Wb[e][o][i] ----
__global__ __launch_bounds__(256)
void pack_w(const float* __restrict__ W, short* __restrict__ Wb) {
    size_t idx = (size_t)blockIdx.x * 256 + threadIdx.x;  // 524288 threads
    const float* src = W + idx * 8;
    f32x4 a = *(const f32x4*)src;
    f32x4 b = *(const f32x4*)(src + 4);
    s16x8 r;
    s16x4 lo = cvt4(a), hi = cvt4(b);
    r[0] = lo[0]; r[1] = lo[1]; r[2] = lo[2]; r[3] = lo[3];
    r[4] = hi[0]; r[5] = hi[1]; r[6] = hi[2]; r[7] = hi[3];
    *(s16x8*)(Wb + idx * 8) = r;
}

// ---- main grouped GEMM ----
__global__ __launch_bounds__(512, 1)
void moe_gemm(const float* __restrict__ X,
              const short* __restrict__ Wb,
              float* __restrict__ Out) {
    // 512 blocks = 8 e x 32 mblk x 2 nblk; XCD-chunk swizzle: one expert/XCD.
    int bid  = blockIdx.x;
    int swz  = (bid & 7) * 64 + (bid >> 3);
    int e    = swz >> 6;
    int rem  = swz & 63;
    int mblk = rem >> 1;
    int nblk = rem & 1;

    const float* Ap = X   + ((size_t)e * NS + (size_t)mblk * BM) * NI;
    const short* Bp = Wb  + ((size_t)e * NO + (size_t)nblk * BN) * NI;
    float*       Cp = Out + ((size_t)e * NS + (size_t)mblk * BM) * NO + nblk * BN;

    __shared__ short lA[2][BM * BK];   // 32 KiB each buf
    __shared__ short lB[2][BN * BK];   // total 128 KiB

    const int tid  = threadIdx.x;
    const int lane = tid & 63;
    const int wid  = tid >> 6;   // 0..7
    const int wm   = wid >> 2;   // 0..1  -> rows [wm*128, +128)
    const int wn   = wid & 3;    // 0..3  -> cols [wn*64, +64)
    const int l15  = lane & 15;
    const int lhi  = lane >> 4;  // 0..3

    f32x4 acc[8][4];
#pragma unroll
    for (int i = 0; i < 8; ++i)
#pragma unroll
        for (int j = 0; j < 4; ++j)
            acc[i][j] = (f32x4){0.f, 0.f, 0.f, 0.f};

    f32x4 ar[8];   // single A staging buffer, halves staggered
    s16x8 af[4], bf_[4];

    // A chunks: u = tid + i*512; row = u>>4 (0..255), c4 = u&15. Coalesced.
    // h=0 -> rows 0..127, h=1 -> rows 128..255 (write-phase disjointness).
#define AISSUE_H(kt, h)                                                        \
    do {                                                                       \
        _Pragma("unroll") for (int i = (h) * 4; i < (h) * 4 + 4; ++i) {        \
            int u = tid + i * 512;                                             \
            ar[i] = *(const f32x4*)(Ap + (size_t)(u >> 4) * NI +               \
                                    (kt) * BK + (u & 15) * 4);                 \
        }                                                                      \
    } while (0)

    // A write: 16B-chunk c16 = c4>>1, phys = c16 ^ (row&7).
#define AWRITE_H(buf, h)                                                       \
    do {                                                                       \
        _Pragma("unroll") for (int i = (h) * 4; i < (h) * 4 + 4; ++i) {        \
            int u    = tid + i * 512;                                          \
            int row  = u >> 4;                                                 \
            int c4   = u & 15;                                                 \
            int phys = (c4 >> 1) ^ (row & 7);                                  \
            *(s16x4*)&lA[buf][row * 64 + phys * 8 + (c4 & 1) * 4] = cvt4(ar[i]); \
        }                                                                      \
    } while (0)

    // B stage via global_load_lds, linear dest, pre-swizzled source (m173).
#define BSTAGE(kt, buf)                                                        \
    do {                                                                       \
        _Pragma("unroll") for (int j = 0; j < 4; ++j) {                        \
            int g    = (wid * 4 + j) * 64 + lane;                              \
            int row  = g >> 3;                                                 \
            int k16  = g & 7;                                                  \
            const short* gp = Bp + (size_t)row * NI + (kt) * BK +              \
                              ((k16 ^ (row & 7)) << 3);                        \
            short* lp = &lB[buf][(wid * 4 + j) * 512];                         \
            __builtin_amdgcn_global_load_lds(                                  \
                (const __attribute__((address_space(1))) void*)gp,             \
                (__attribute__((address_space(3))) void*)lp, 16, 0, 0);        \
        }                                                                      \
    } while (0)

#define PH_READ_A(c, kk, mh)                                                   \
    do {                                                                       \
        _Pragma("unroll") for (int j = 0; j < 4; ++j) {                        \
            int r    = wm * 128 + ((mh) * 4 + j) * 16 + l15;                   \
            int phys = ((kk) * 4 + lhi) ^ (r & 7);                             \
            af[j]    = *(const s16x8*)&lA[c][r * 64 + phys * 8];               \
        }                                                                      \
    } while (0)

#define PH_READ_B(c, kk)                                                       \
    do {                                                                       \
        _Pragma("unroll") for (int ni = 0; ni < 4; ++ni) {                     \
            int rb   = wn * 64 + ni * 16 + l15;                                \
            int phys = ((kk) * 4 + lhi) ^ (rb & 7);                            \
            bf_[ni]  = *(const s16x8*)&lB[c][rb * 64 + phys * 8];              \
        }                                                                      \
    } while (0)

#define PH_MFMA(mh)                                                            \
    do {                                                                       \
        __builtin_amdgcn_s_setprio(1);                                         \
        _Pragma("unroll") for (int j = 0; j < 4; ++j)                          \
            _Pragma("unroll") for (int ni = 0; ni < 4; ++ni)                   \
                acc[(mh) * 4 + j][ni] = __builtin_amdgcn_mfma_f32_16x16x32_bf16( \
                    af[j], bf_[ni], acc[(mh) * 4 + j][ni], 0, 0, 0);           \
        __builtin_amdgcn_s_setprio(0);                                         \
    } while (0)

#define BAR()   __builtin_amdgcn_s_barrier()
#define LGKM0() asm volatile("s_waitcnt lgkmcnt(0)" ::: "memory")
#define VM(n)   asm volatile("s_waitcnt vmcnt(" #n ")" ::: "memory")

    // ---- Prologue: stage tile 0; leave A8(1) in flight (loop invariant:
    //      entering P1(kt): outstanding = [Ah0(kt+1), Ah1(kt+1)] = 8. ----
    AISSUE_H(0, 0); AISSUE_H(0, 1);
    VM(0);
    AWRITE_H(0, 0); AWRITE_H(0, 1);
    BSTAGE(0, 0);                       // B4(0)
    AISSUE_H(1, 0); AISSUE_H(1, 1);     // A8(1)
    VM(8);                              // drain B4(0), keep A8(1)
    LGKM0();                            // my A ds_writes visible
    BAR();

#pragma unroll 1
    for (int kt = 0; kt < NT; ++kt) {
        const int c = kt & 1;
        // ---- P1 (read-only): kk0, mi 0-3 ----
        PH_READ_B(c, 0);
        PH_READ_A(c, 0, 0);
        LGKM0();
        PH_MFMA(0);
        BAR();
        // ---- P2 (writes: A-h0 rows 0-127 + B-DMA): kk0, mi 4-7 ----
        if (kt + 1 < NT) {
            VM(4);                      // ar[0-3] = A-h0(kt+1) ready
            AWRITE_H(c ^ 1, 0);
            BSTAGE(kt + 1, c ^ 1);
        }
        if (kt + 2 < NT) AISSUE_H(kt + 2, 0);
        PH_READ_A(c, 0, 1);
        LGKM0();
        PH_MFMA(1);
        BAR();
        // ---- P3 (writes: A-h1 rows 128-255): kk1, mi 0-3 ----
        if (kt + 1 < NT) {
            if (kt + 2 < NT) { VM(8); } else { VM(4); }   // ar[4-7] ready
            AWRITE_H(c ^ 1, 1);
        }
        if (kt + 2 < NT) AISSUE_H(kt + 2, 1);
        PH_READ_B(c, 1);
        PH_READ_A(c, 1, 0);
        LGKM0();
        PH_MFMA(0);
        BAR();
        // ---- P4 (read-only): kk1, mi 4-7; drain B-DMA(kt+1), keep A8 ----
        PH_READ_A(c, 1, 1);
        if (kt + 2 < NT)      { VM(8); }
        else if (kt + 1 < NT) { VM(0); }
        LGKM0();
        PH_MFMA(1);
        BAR();
    }

    // Epilogue: D frag (mi,ni): m = lhi*4 + rr, n = l15 (verified layout).
#pragma unroll
    for (int mi = 0; mi < 8; ++mi) {
#pragma unroll
        for (int rr = 0; rr < 4; ++rr) {
            int row   = wm * 128 + mi * 16 + lhi * 4 + rr;
            float* cp = Cp + (size_t)row * NO + wn * 64 + l15;
#pragma unroll
            for (int ni = 0; ni < 4; ++ni)
                cp[ni * 16] = acc[mi][ni][rr];
        }
    }
#undef AISSUE_H
#undef AWRITE_H
#undef BSTAGE
#undef PH_READ_A
#undef PH_READ_B
#undef PH_MFMA
#undef BAR
#undef LGKM0
#undef VM
}

extern "C" void kernel_launch(void* const* d_in, const int* in_sizes, int n_in,
                              void* d_out, int out_size, void* d_ws, size_t ws_size,
                              hipStream_t stream) {
    const float* X = (const float*)d_in[0];
    const float* W = (const float*)d_in[1];
    float* Out     = (float*)d_out;
    short* Wb      = (short*)d_ws;   // 8 MiB bf16 W

    hipLaunchKernelGGL(pack_w, dim3(2048), dim3(256), 0, stream, W, Wb);
    hipLaunchKernelGGL(moe_gemm, dim3(NE * (NS / BM) * (NO / BN)), dim3(512), 0,
                       stream, X, Wb, Out);
}

// Round 11
// 116.798 us; speedup vs baseline: 1.1438x; 1.1438x over previous
//
#include <hip/hip_runtime.h>
#include <hip/hip_bf16.h>

// Grouped GEMM: out[e,s,o] = sum_i x[e,s,i] * w[e,o,i]
// E=8, S=8192 tok/expert, O=512, I=1024, fp32 in/out, bf16 MFMA compute.
// R11: LDS-pool cut. BN=512 (full N) x BM=128, BK=32, 8 waves (1Mx8N).
//      B reg-direct from fragment-packed Wpk (R3-proven), double-buffered
//      in named regs -> zero B LDS traffic. A reg-staged fp32->bf16 into
//      padded LDS (row stride 40 shorts; even bank spread, no swizzle).
//      One phase/tile: VM(4); AWRITE; AISSUE(kt+2); 8 ds_read; 32 MFMA;
//      BLOAD(kt+2); lgkm0; bar.  vmcnt never 0 mid-loop.

#define NE 8
#define NO 512
#define NI 1024
#define NS 8192

#define BM 128
#define BK 32
#define NT (NI / BK)   // 32 K-tiles
#define LDA 40         // padded A row stride in shorts (32 data + 8 pad)

typedef __attribute__((ext_vector_type(4))) float f32x4;
typedef __attribute__((ext_vector_type(4))) short s16x4;
typedef __attribute__((ext_vector_type(8))) short s16x8;

__device__ __forceinline__ s16x4 cvt4(f32x4 a) {
    s16x4 r;
    r[0] = (short)__builtin_bit_cast(unsigned short, __float2bfloat16(a[0]));
    r[1] = (short)__builtin_bit_cast(unsigned short, __float2bfloat16(a[1]));
    r[2] = (short)__builtin_bit_cast(unsigned short, __float2bfloat16(a[2]));
    r[3] = (short)__builtin_bit_cast(unsigned short, __float2bfloat16(a[3]));
    return r;
}

// ---- pass 0: W fp32 -> bf16, MFMA B-fragment lane order (R3-verified) ----
// Wpk(e, g, kt32, l, j) = bf16(W[e][g*16 + (l&15)][kt32*32 + (l>>4)*8 + j])
__global__ __launch_bounds__(256)
void pack_w(const float* __restrict__ W, short* __restrict__ Wpk) {
    int idx  = blockIdx.x * 256 + threadIdx.x;  // 0 .. 524287
    int l    = idx & 63;
    int kt32 = (idx >> 6) & 31;
    int g    = (idx >> 11) & 31;
    int e    = idx >> 16;
    const float* src = W + (size_t)(e * NO + g * 16 + (l & 15)) * NI
                         + kt32 * 32 + (l >> 4) * 8;
    f32x4 a = *(const f32x4*)src;
    f32x4 b = *(const f32x4*)(src + 4);
    s16x4 lo = cvt4(a), hi = cvt4(b);
    s16x8 r;
    r[0] = lo[0]; r[1] = lo[1]; r[2] = lo[2]; r[3] = lo[3];
    r[4] = hi[0]; r[5] = hi[1]; r[6] = hi[2]; r[7] = hi[3];
    *(s16x8*)(Wpk + (size_t)idx * 8) = r;
}

// ---- main grouped GEMM ----
__global__ __launch_bounds__(512, 1)
void moe_gemm(const float* __restrict__ X,
              const short* __restrict__ Wpk,
              float* __restrict__ Out) {
    // 512 blocks = 8 experts x 64 mblk. e = bid&7: consecutive blocks
    // round-robin XCDs -> each XCD runs one expert (Wpk_e 1 MB L2-resident).
    int bid  = blockIdx.x;
    int e    = bid & 7;
    int mblk = bid >> 3;

    const float* Ap = X   + ((size_t)e * NS + (size_t)mblk * BM) * NI;
    const short* Bp = Wpk + (size_t)e * (32 * 32 * 64 * 8);
    float*       Cp = Out + ((size_t)e * NS + (size_t)mblk * BM) * NO;

    __shared__ short lA[2][BM * LDA];   // 2 x 10 KiB

    const int tid  = threadIdx.x;
    const int lane = tid & 63;
    const int wn   = tid >> 6;    // 0..7 -> cols [wn*64, +64)
    const int l15  = lane & 15;
    const int lhi  = lane >> 4;   // 0..3

    f32x4 acc[8][4];
#pragma unroll
    for (int i = 0; i < 8; ++i)
#pragma unroll
        for (int j = 0; j < 4; ++j)
            acc[i][j] = (f32x4){0.f, 0.f, 0.f, 0.f};

    f32x4 ar[2];                 // A staging: 2 x f32x4 / thread
    s16x8 bfA[4], bfB[4], af[8]; // named B double-buffer (rule #20)

    // A: unit u = tid + i*512 over 1024 f32x4-chunks of the 128x32 tile.
    // row = u>>3 (0..127), c4 = u&7. Coalesced 128 B per row per wave-slice.
#define AISSUE(kt)                                                             \
    do {                                                                       \
        _Pragma("unroll") for (int i = 0; i < 2; ++i) {                        \
            int u = tid + i * 512;                                             \
            ar[i] = *(const f32x4*)(Ap + (size_t)(u >> 3) * NI +               \
                                    (kt) * BK + (u & 7) * 4);                  \
        }                                                                      \
    } while (0)

#define AWRITE(buf)                                                            \
    do {                                                                       \
        _Pragma("unroll") for (int i = 0; i < 2; ++i) {                        \
            int u = tid + i * 512;                                             \
            *(s16x4*)&lA[buf][(u >> 3) * LDA + (u & 7) * 4] = cvt4(ar[i]);     \
        }                                                                      \
    } while (0)

    // B frag (wn*4+ni, kt): 16 B/lane, consecutive lanes contiguous (L2).
#define BLOAD(kt, dst)                                                         \
    do {                                                                       \
        _Pragma("unroll") for (int ni = 0; ni < 4; ++ni)                       \
            dst[ni] = *(const s16x8*)(Bp +                                     \
                ((size_t)((wn * 4 + ni) * 32 + (kt)) * 64 + lane) * 8);        \
    } while (0)

    // A frags: row mi*16+l15, k-chunk lhi (16 B). Pad spreads banks evenly.
#define READA(c)                                                               \
    do {                                                                       \
        _Pragma("unroll") for (int mi = 0; mi < 8; ++mi)                       \
            af[mi] = *(const s16x8*)&lA[c][(mi * 16 + l15) * LDA + lhi * 8];   \
    } while (0)

#define MFMA(bf)                                                               \
    do {                                                                       \
        __builtin_amdgcn_s_setprio(1);                                         \
        _Pragma("unroll") for (int mi = 0; mi < 8; ++mi)                       \
            _Pragma("unroll") for (int ni = 0; ni < 4; ++ni)                   \
                acc[mi][ni] = __builtin_amdgcn_mfma_f32_16x16x32_bf16(         \
                    af[mi], bf[ni], acc[mi][ni], 0, 0, 0);                     \
        __builtin_amdgcn_s_setprio(0);                                         \
    } while (0)

#define BAR()   __builtin_amdgcn_s_barrier()
#define LGKM0() asm volatile("s_waitcnt lgkmcnt(0)" ::: "memory")
#define VM(n)   asm volatile("s_waitcnt vmcnt(" #n ")" ::: "memory")

    // ---- Prologue. Invariant entering tile kt: lA[kt&1]=A(kt) staged,
    //      bf_cur=B(kt) ready, outstanding vm = A2(kt+1), B4(kt+1). ----
    AISSUE(0);
    VM(0);
    AWRITE(0);
    BLOAD(0, bfA);     // B4(0)
    AISSUE(1);         // A2(1)
    BLOAD(1, bfB);     // B4(1)
    VM(6);             // drain B4(0); keep A2(1)+B4(1)
    LGKM0();
    BAR();

    // Main tile: drains A2(kt+1)+[next iter: B4(kt+1)] via VM(4).
#define TILE_MAIN(kt, bfc)                                                     \
    do {                                                                       \
        VM(4);                      /* A2(kt+1) ready; B4(kt+1) in flight */   \
        AWRITE(((kt) + 1) & 1);                                                \
        AISSUE((kt) + 2);                                                      \
        READA((kt) & 1);                                                       \
        MFMA(bfc);                                                             \
        BLOAD((kt) + 2, bfc);       /* reuse just-consumed buffer */           \
        LGKM0();                                                               \
        BAR();                                                                 \
    } while (0)

#pragma unroll 1
    for (int kt2 = 0; kt2 < NT / 2 - 1; ++kt2) {
        const int kt = kt2 * 2;
        TILE_MAIN(kt, bfA);
        TILE_MAIN(kt + 1, bfB);
    }
    // Tail: kt = 30, 31.
    {
        VM(4);                      // drain A2(31); keep B4(31)
        AWRITE(1);
        READA(0);
        MFMA(bfA);
        LGKM0();
        BAR();
        VM(0);                      // drain B4(31)
        READA(1);
        MFMA(bfB);
    }

    // Epilogue: D frag (mi,ni): m = lhi*4 + rr, n = l15 (verified layout).
#pragma unroll
    for (int mi = 0; mi < 8; ++mi) {
#pragma unroll
        for (int rr = 0; rr < 4; ++rr) {
            int row   = mi * 16 + lhi * 4 + rr;
            float* cp = Cp + (size_t)row * NO + wn * 64 + l15;
#pragma unroll
            for (int ni = 0; ni < 4; ++ni)
                cp[ni * 16] = acc[mi][ni][rr];
        }
    }
#undef AISSUE
#undef AWRITE
#undef BLOAD
#undef READA
#undef MFMA
#undef TILE_MAIN
#undef BAR
#undef LGKM0
#undef VM
}

extern "C" void kernel_launch(void* const* d_in, const int* in_sizes, int n_in,
                              void* d_out, int out_size, void* d_ws, size_t ws_size,
                              hipStream_t stream) {
    const float* X = (const float*)d_in[0];
    const float* W = (const float*)d_in[1];
    float* Out     = (float*)d_out;
    short* Wpk     = (short*)d_ws;   // 8 MiB

    hipLaunchKernelGGL(pack_w, dim3(2048), dim3(256), 0, stream, W, Wpk);
    hipLaunchKernelGGL(moe_gemm, dim3(NE * (NS / BM)), dim3(512), 0,
                       stream, X, Wpk, Out);
}